// Round 8
// baseline (352.077 us; speedup 1.0000x reference)
//
#include <hip/hip_runtime.h>
#include <hip/hip_bf16.h>
#include <hip/hip_cooperative_groups.h>

namespace cg = cooperative_groups;

// GNN layer: h1 = A @ x (fixed stencil), out = h1 @ W^T + bias
// x[64][65536] f32, W[256][65536] f32, bias[256], out[64][256] f32.
// Single cooperative kernel: stencil -> grid.sync -> bf16-MFMA gemm ->
// grid.sync -> deterministic reduce. 512 blocks x 512 thr, 2/CU co-resident.

#define MB     64
#define NOUT   256
#define KDIM   65536
#define NTOT   (MB * KDIM)
#define KP     2048              // k per gemm block
#define NKP    (KDIM / KP)       // 32 partial chunks
#define OTOT   (MB * NOUT)       // 16384

typedef __attribute__((ext_vector_type(8))) short bf16x8;
typedef __attribute__((ext_vector_type(8))) unsigned short ushort8v;
typedef __attribute__((ext_vector_type(4))) float f32x4;

__device__ __forceinline__ ushort f2bf(float f) {
    __hip_bfloat16 h = __float2bfloat16(f);
    return *reinterpret_cast<ushort*>(&h);
}

// ---------------------------------------------------------------------------
// Stencil body: 8 elems starting at flat index g (g multiple of 8).
// h1[b,i] = x[b,i] + sum_o ([center(i)]+[center(i+o)])*x[b,i+o];
// centers = flat 257..65278 (matches reference COO construction).
// Clamped OOB loads only feed weight-0 terms.
// ---------------------------------------------------------------------------
__device__ __forceinline__ void stencil8(const float* __restrict__ x,
                                         ushort* __restrict__ h1, int g) {
    const int i8 = g & (KDIM - 1);
    union Span { float4 v[4]; float f[16]; };
    Span u, c, d;
    #pragma unroll
    for (int q = 0; q < 4; ++q) {
        int bu = g - 260 + 4 * q; if (bu < 0) bu = 0;
        int bc = g - 4   + 4 * q; if (bc < 0) bc = 0; if (bc > NTOT - 4) bc = NTOT - 4;
        int bd = g + 252 + 4 * q; if (bd > NTOT - 4) bd = NTOT - 4;
        u.v[q] = *(const float4*)(x + bu);
        c.v[q] = *(const float4*)(x + bc);
        d.v[q] = *(const float4*)(x + bd);
    }
    ushort8v ov;
    if (i8 >= 520 && i8 <= 65008) {          // fast path: everything interior
        #pragma unroll
        for (int e = 0; e < 8; ++e) {
            float nb = c.f[3 + e] + c.f[5 + e]
                     + u.f[3 + e] + u.f[4 + e] + u.f[5 + e]
                     + d.f[3 + e] + d.f[4 + e] + d.f[5 + e];
            ov[e] = (short)f2bf(fmaf(2.0f, nb, c.f[4 + e]));
        }
    } else {
        #pragma unroll
        for (int e = 0; e < 8; ++e) {
            const int ii = i8 + e;
            const float ci = ((unsigned)(ii - 257) <= (65278u - 257u)) ? 1.0f : 0.0f;
            float s = c.f[4 + e];
            const int   doff[8] = {-1, 1, -257, -256, -255, 255, 256, 257};
            const float* src[8] = {&c.f[3 + e], &c.f[5 + e],
                                   &u.f[3 + e], &u.f[4 + e], &u.f[5 + e],
                                   &d.f[3 + e], &d.f[4 + e], &d.f[5 + e]};
            #pragma unroll
            for (int t = 0; t < 8; ++t) {
                const int j = ii + doff[t];
                const float cj = ((unsigned)(j - 257) <= (65278u - 257u)) ? 1.0f : 0.0f;
                s = fmaf(ci + cj, *src[t], s);
            }
            ov[e] = (short)f2bf(s);
        }
    }
    *(ushort8v*)(h1 + g) = ov;
}

// ---------------------------------------------------------------------------
// Fused cooperative kernel. 512 blocks x 512 threads, 32 KiB LDS.
// ---------------------------------------------------------------------------
__global__ __launch_bounds__(512, 4) void fused_gnn(const float* __restrict__ x,
                                                    const float* __restrict__ W,
                                                    const float* __restrict__ bias,
                                                    ushort* __restrict__ h1,
                                                    float* __restrict__ part,
                                                    float* __restrict__ out) {
    __shared__ float red[8 * 1024];      // 32 KiB
    cg::grid_group grid = cg::this_grid();

    // ---- Phase 1: stencil (each thread: 16 elems) ----
    {
        const int flat = blockIdx.x * 512 + threadIdx.x;   // 0..262143
        const int g = flat * 16;
        stencil8(x, h1, g);
        stencil8(x, h1, g + 8);
    }
    __threadfence();
    grid.sync();

    // ---- Phase 2: MFMA gemm. Logical block (nt, kp), XCD-swizzled. ----
    {
        const int d   = blockIdx.x;
        const int xcd = d & 7;
        const int idx = d >> 3;
        const int nt  = idx & 15;
        const int kp  = xcd + 8 * (idx >> 4);
        const int wv  = threadIdx.x >> 6;    // 0..7, 256 k each
        const int l   = threadIdx.x & 63;
        const int lr  = l & 15;
        const int lg  = l >> 4;
        const size_t kb = (size_t)kp * KP + wv * 256 + lg * 8;

        f32x4 acc[4];
        #pragma unroll
        for (int a = 0; a < 4; ++a) acc[a] = (f32x4){0.f, 0.f, 0.f, 0.f};

        const ushort* ap = h1 + (size_t)lr * KDIM + kb;
        const float*  wp = W + (size_t)(nt * 16 + lr) * KDIM + kb;

        #pragma unroll
        for (int ks = 0; ks < 8; ++ks) {     // 8 x 32-k steps
            bf16x8 afrag[4];
            #pragma unroll
            for (int mt = 0; mt < 4; ++mt)
                afrag[mt] = *(const bf16x8*)(ap + (size_t)mt * 16 * KDIM + ks * 32);
            float4 w0 = *(const float4*)(wp + ks * 32);
            float4 w1 = *(const float4*)(wp + ks * 32 + 4);
            union { ushort u[8]; bf16x8 v; } bb;
            bb.u[0] = f2bf(w0.x); bb.u[1] = f2bf(w0.y);
            bb.u[2] = f2bf(w0.z); bb.u[3] = f2bf(w0.w);
            bb.u[4] = f2bf(w1.x); bb.u[5] = f2bf(w1.y);
            bb.u[6] = f2bf(w1.z); bb.u[7] = f2bf(w1.w);
            #pragma unroll
            for (int mt = 0; mt < 4; ++mt)
                acc[mt] = __builtin_amdgcn_mfma_f32_16x16x32_bf16(afrag[mt], bb.v,
                                                                  acc[mt], 0, 0, 0);
        }

        // D layout: ncol = lane&15, m = (lane>>4)*4 + reg (m89/m91-verified).
        #pragma unroll
        for (int mt = 0; mt < 4; ++mt)
            #pragma unroll
            for (int r = 0; r < 4; ++r)
                red[wv * 1024 + (mt * 16 + lg * 4 + r) * 16 + lr] = acc[mt][r];
        __syncthreads();

        // combine 8 wave-tiles: thread t owns local outputs t and t+512
        #pragma unroll
        for (int h = 0; h < 2; ++h) {
            const int o = threadIdx.x + h * 512;     // m_local*16 + ncol
            float s0 = 0.f, s1 = 0.f;
            #pragma unroll
            for (int j = 0; j < 8; j += 2) {
                s0 += red[j * 1024 + o];
                s1 += red[(j + 1) * 1024 + o];
            }
            part[(size_t)kp * OTOT + (o >> 4) * NOUT + nt * 16 + (o & 15)] = s0 + s1;
        }
    }
    __threadfence();
    grid.sync();

    // ---- Phase 3: reduce 32 partials (+bias). Block b -> 32 outputs. ----
    if (threadIdx.x < 256) {
        const int ol = threadIdx.x & 31;
        const int cgp = threadIdx.x >> 5;            // 0..7 -> 4 chunks each
        const int o  = blockIdx.x * 32 + ol;         // 0..16383
        const float* p = part + (size_t)cgp * 4 * OTOT + o;
        float v = (p[0] + p[OTOT]) + (p[2 * OTOT] + p[3 * OTOT]);
        __syncthreads();
        red[threadIdx.x] = v;
        __syncthreads();
        if (cgp == 0) {
            float s = red[ol];
            #pragma unroll
            for (int jj = 1; jj < 8; ++jj) s += red[jj * 32 + ol];
            out[o] = s + bias[o & (NOUT - 1)];
        }
    } else {
        __syncthreads();   // match phase-3 barriers
        __syncthreads();
    }
}

// ---------------------------------------------------------------------------
// Fallback (non-cooperative) path: R7's three kernels.
// ---------------------------------------------------------------------------
__global__ __launch_bounds__(256) void stencil_bf16(const float* __restrict__ x,
                                                    ushort* __restrict__ h1) {
    const int g = (blockIdx.x * 256 + threadIdx.x) * 8;
    stencil8(x, h1, g);
}

__global__ __launch_bounds__(1024, 4) void gemm_mfma(const ushort* __restrict__ h1,
                                                     const float* __restrict__ W,
                                                     float* __restrict__ part) {
    __shared__ float red[16 * 1024];
    const int d   = blockIdx.x;
    const int xcd = d & 7;
    const int idx = d >> 3;
    const int nt  = idx & 15;
    const int kp  = xcd + 8 * (idx >> 4);
    const int wv = threadIdx.x >> 6;
    const int l  = threadIdx.x & 63;
    const int lr = l & 15;
    const int lg = l >> 4;
    const size_t kb = (size_t)kp * KP + wv * 128 + lg * 8;

    f32x4 acc[4];
    #pragma unroll
    for (int a = 0; a < 4; ++a) acc[a] = (f32x4){0.f, 0.f, 0.f, 0.f};
    const ushort* ap = h1 + (size_t)lr * KDIM + kb;
    const float*  wp = W + (size_t)(nt * 16 + lr) * KDIM + kb;
    #pragma unroll
    for (int ks = 0; ks < 4; ++ks) {
        bf16x8 afrag[4];
        #pragma unroll
        for (int mt = 0; mt < 4; ++mt)
            afrag[mt] = *(const bf16x8*)(ap + (size_t)mt * 16 * KDIM + ks * 32);
        float4 w0 = *(const float4*)(wp + ks * 32);
        float4 w1 = *(const float4*)(wp + ks * 32 + 4);
        union { ushort u[8]; bf16x8 v; } bb;
        bb.u[0] = f2bf(w0.x); bb.u[1] = f2bf(w0.y);
        bb.u[2] = f2bf(w0.z); bb.u[3] = f2bf(w0.w);
        bb.u[4] = f2bf(w1.x); bb.u[5] = f2bf(w1.y);
        bb.u[6] = f2bf(w1.z); bb.u[7] = f2bf(w1.w);
        #pragma unroll
        for (int mt = 0; mt < 4; ++mt)
            acc[mt] = __builtin_amdgcn_mfma_f32_16x16x32_bf16(afrag[mt], bb.v,
                                                              acc[mt], 0, 0, 0);
    }
    #pragma unroll
    for (int mt = 0; mt < 4; ++mt)
        #pragma unroll
        for (int r = 0; r < 4; ++r)
            red[wv * 1024 + (mt * 16 + lg * 4 + r) * 16 + lr] = acc[mt][r];
    __syncthreads();
    const int t = threadIdx.x;
    float s0 = 0.f, s1 = 0.f;
    #pragma unroll
    for (int j = 0; j < 16; j += 2) {
        s0 += red[j * 1024 + t];
        s1 += red[(j + 1) * 1024 + t];
    }
    part[(size_t)kp * OTOT + (t >> 4) * NOUT + nt * 16 + (t & 15)] = s0 + s1;
}

__global__ __launch_bounds__(256) void reduce_f32(const float* __restrict__ part,
                                                  const float* __restrict__ bias,
                                                  float* __restrict__ out) {
    __shared__ float red[256];
    const int ol = threadIdx.x & 31;
    const int cgp = threadIdx.x >> 5;
    const int o  = blockIdx.x * 32 + ol;
    const float* p = part + (size_t)cgp * 4 * OTOT + o;
    red[threadIdx.x] = (p[0] + p[OTOT]) + (p[2 * OTOT] + p[3 * OTOT]);
    __syncthreads();
    if (cgp == 0) {
        float v = red[ol];
        #pragma unroll
        for (int jj = 1; jj < 8; ++jj) v += red[jj * 32 + ol];
        out[o] = v + bias[o & (NOUT - 1)];
    }
}

// ---------------------------------------------------------------------------
extern "C" void kernel_launch(void* const* d_in, const int* in_sizes, int n_in,
                              void* d_out, int out_size, void* d_ws, size_t ws_size,
                              hipStream_t stream) {
    const float* x    = (const float*)d_in[0];
    const float* W    = (const float*)d_in[1];
    const float* bias = (const float*)d_in[2];
    float* out = (float*)d_out;

    ushort* h1b  = (ushort*)d_ws;                                  // 8 MiB
    float*  part = (float*)((char*)d_ws + (size_t)MB * KDIM * 2);  // 2 MiB

    void* args[6];
    const float* xa = x; const float* Wa = W; const float* ba = bias;
    ushort* ha = h1b; float* pa = part; float* oa = out;
    args[0] = &xa; args[1] = &Wa; args[2] = &ba;
    args[3] = &ha; args[4] = &pa; args[5] = &oa;

    hipError_t rc = hipLaunchCooperativeKernel((void*)fused_gnn,
                                               dim3(512), dim3(512),
                                               args, 0, stream);
    if (rc != hipSuccess) {
        // fallback: three-kernel path (R7)
        stencil_bf16<<<NTOT / (256 * 8), 256, 0, stream>>>(x, h1b);
        gemm_mfma<<<16 * NKP, 1024, 0, stream>>>(h1b, W, part);
        reduce_f32<<<OTOT / 32, 256, 0, stream>>>(part, bias, out);
    }
}

// Round 9
// 62.737 us; speedup vs baseline: 5.6120x; 5.6120x over previous
//
#include <hip/hip_runtime.h>
#include <hip/hip_bf16.h>

// GNN layer: h1 = A @ x (fixed stencil), out = h1 @ W^T + bias
// x[64][65536] f32, W[256][65536] f32, bias[256], out[64][256] f32.
// 3 kernels: stencil -> wave-owns-tile bf16 MFMA gemm (no LDS, no barriers)
// -> deterministic reduce.

#define MB     64
#define NOUT   256
#define KDIM   65536
#define NTOT   (MB * KDIM)
#define KP     1024              // k per gemm block
#define NKP    (KDIM / KP)       // 64 partial chunks
#define OTOT   (MB * NOUT)       // 16384

typedef __attribute__((ext_vector_type(8))) short bf16x8;
typedef __attribute__((ext_vector_type(8))) unsigned short ushort8v;
typedef __attribute__((ext_vector_type(4))) float f32x4;

__device__ __forceinline__ ushort f2bf(float f) {
    __hip_bfloat16 h = __float2bfloat16(f);
    return *reinterpret_cast<ushort*>(&h);
}

// ---------------------------------------------------------------------------
// Stencil body: 8 elems at flat index g. h1[b,i] = x[b,i] +
// sum_o ([center(i)]+[center(i+o)])*x[b,i+o]; centers = flat 257..65278
// (matches reference COO). Clamped OOB loads only feed weight-0 terms.
// ---------------------------------------------------------------------------
__device__ __forceinline__ void stencil8(const float* __restrict__ x,
                                         ushort* __restrict__ h1, int g) {
    const int i8 = g & (KDIM - 1);
    union Span { float4 v[4]; float f[16]; };
    Span u, c, d;
    #pragma unroll
    for (int q = 0; q < 4; ++q) {
        int bu = g - 260 + 4 * q; if (bu < 0) bu = 0;
        int bc = g - 4   + 4 * q; if (bc < 0) bc = 0; if (bc > NTOT - 4) bc = NTOT - 4;
        int bd = g + 252 + 4 * q; if (bd > NTOT - 4) bd = NTOT - 4;
        u.v[q] = *(const float4*)(x + bu);
        c.v[q] = *(const float4*)(x + bc);
        d.v[q] = *(const float4*)(x + bd);
    }
    ushort8v ov;
    if (i8 >= 520 && i8 <= 65008) {          // fast path: everything interior
        #pragma unroll
        for (int e = 0; e < 8; ++e) {
            float nb = c.f[3 + e] + c.f[5 + e]
                     + u.f[3 + e] + u.f[4 + e] + u.f[5 + e]
                     + d.f[3 + e] + d.f[4 + e] + d.f[5 + e];
            ov[e] = (short)f2bf(fmaf(2.0f, nb, c.f[4 + e]));
        }
    } else {
        #pragma unroll
        for (int e = 0; e < 8; ++e) {
            const int ii = i8 + e;
            const float ci = ((unsigned)(ii - 257) <= (65278u - 257u)) ? 1.0f : 0.0f;
            float s = c.f[4 + e];
            const int   doff[8] = {-1, 1, -257, -256, -255, 255, 256, 257};
            const float* src[8] = {&c.f[3 + e], &c.f[5 + e],
                                   &u.f[3 + e], &u.f[4 + e], &u.f[5 + e],
                                   &d.f[3 + e], &d.f[4 + e], &d.f[5 + e]};
            #pragma unroll
            for (int t = 0; t < 8; ++t) {
                const int j = ii + doff[t];
                const float cj = ((unsigned)(j - 257) <= (65278u - 257u)) ? 1.0f : 0.0f;
                s = fmaf(ci + cj, *src[t], s);
            }
            ov[e] = (short)f2bf(s);
        }
    }
    *(ushort8v*)(h1 + g) = ov;
}

__global__ __launch_bounds__(256) void stencil_bf16(const float* __restrict__ x,
                                                    ushort* __restrict__ h1) {
    const int g = (blockIdx.x * 256 + threadIdx.x) * 8;
    stencil8(x, h1, g);
}

// ---------------------------------------------------------------------------
// Wave-owns-tile MFMA GEMM. Logical block (nt, kp): n-tile nt (16 cols),
// k in [kp*1024, +1024). XCD swizzle: d%8 == kp%8 -> all 16 nt-blocks of a kp
// share one XCD's L2 copy of the h1 slice. 4 waves; wave = m-tile mt.
// Each wave: 16x16 f32 acc over 32 chained MFMA. No LDS, no barriers.
// part layout [kp][n][m] f32; lane stores 4 consecutive m as one float4.
// ---------------------------------------------------------------------------
__global__ __launch_bounds__(256, 4) void gemm_mfma(const ushort* __restrict__ h1,
                                                    const float* __restrict__ W,
                                                    float* __restrict__ part) {
    const int d   = blockIdx.x;          // 0..1023 (swizzled)
    const int xcd = d & 7;
    const int idx = d >> 3;              // 0..127
    const int nt  = idx & 15;
    const int kp  = xcd + 8 * (idx >> 4);    // 0..63
    const int mt  = threadIdx.x >> 6;    // 0..3 = m-tile (wave role)
    const int l   = threadIdx.x & 63;
    const int lr  = l & 15;
    const int lg  = l >> 4;
    const size_t kb = (size_t)kp * KP + lg * 8;

    f32x4 acc = (f32x4){0.f, 0.f, 0.f, 0.f};

    const ushort* ap = h1 + (size_t)(mt * 16 + lr) * KDIM + kb;
    const float*  wp = W + (size_t)(nt * 16 + lr) * KDIM + kb;

    #pragma unroll 8
    for (int ks = 0; ks < KP / 32; ++ks) {   // 32 steps of K=32
        bf16x8 afrag = *(const bf16x8*)(ap + ks * 32);
        float4 w0 = *(const float4*)(wp + ks * 32);
        float4 w1 = *(const float4*)(wp + ks * 32 + 4);
        union { ushort u[8]; bf16x8 v; } bb;
        bb.u[0] = f2bf(w0.x); bb.u[1] = f2bf(w0.y);
        bb.u[2] = f2bf(w0.z); bb.u[3] = f2bf(w0.w);
        bb.u[4] = f2bf(w1.x); bb.u[5] = f2bf(w1.y);
        bb.u[6] = f2bf(w1.z); bb.u[7] = f2bf(w1.w);
        acc = __builtin_amdgcn_mfma_f32_16x16x32_bf16(afrag, bb.v, acc, 0, 0, 0);
    }

    // D layout: n-col = lane&15, m = (lane>>4)*4 + reg (m89/m91-verified).
    // part[kp][n][m]: lane's 4 m are consecutive -> one float4 store.
    float* pb = part + (size_t)kp * OTOT + (size_t)(nt * 16 + lr) * MB
              + mt * 16 + lg * 4;
    *(f32x4*)pb = acc;
}

// ---------------------------------------------------------------------------
// Reduce 64 f32 partials (+bias) -> out[64][256]. 512 blocks, 8 thr/output,
// 8 chunks each, LDS combine. part[kp][n*64+m]; out[m][n].
// ---------------------------------------------------------------------------
__global__ __launch_bounds__(256) void reduce_f32(const float* __restrict__ part,
                                                  const float* __restrict__ bias,
                                                  float* __restrict__ out) {
    __shared__ float red[256];
    const int ol = threadIdx.x & 31;
    const int cg = threadIdx.x >> 5;               // 0..7 -> 8 chunks each
    const int o  = blockIdx.x * 32 + ol;           // 0..16383
    const float* p = part + (size_t)cg * 8 * OTOT + o;
    float s0 = 0.f, s1 = 0.f, s2 = 0.f, s3 = 0.f;
    #pragma unroll
    for (int i = 0; i < 8; i += 4) {
        s0 += p[(size_t)(i + 0) * OTOT];
        s1 += p[(size_t)(i + 1) * OTOT];
        s2 += p[(size_t)(i + 2) * OTOT];
        s3 += p[(size_t)(i + 3) * OTOT];
    }
    red[threadIdx.x] = (s0 + s1) + (s2 + s3);
    __syncthreads();
    if (cg == 0) {
        float v = red[ol];
        #pragma unroll
        for (int jj = 1; jj < 8; ++jj) v += red[jj * 32 + ol];
        const int n = o >> 6, m = o & 63;
        out[m * NOUT + n] = v + bias[n];
    }
}

// ---------------------------------------------------------------------------
extern "C" void kernel_launch(void* const* d_in, const int* in_sizes, int n_in,
                              void* d_out, int out_size, void* d_ws, size_t ws_size,
                              hipStream_t stream) {
    const float* x    = (const float*)d_in[0];
    const float* W    = (const float*)d_in[1];
    const float* bias = (const float*)d_in[2];
    float* out = (float*)d_out;

    ushort* h1b  = (ushort*)d_ws;                                  // 8 MiB
    float*  part = (float*)((char*)d_ws + (size_t)MB * KDIM * 2);  // 4 MiB

    stencil_bf16<<<NTOT / (256 * 8), 256, 0, stream>>>(x, h1b);
    gemm_mfma<<<16 * NKP, 256, 0, stream>>>(h1b, W, part);
    reduce_f32<<<OTOT / 32, 256, 0, stream>>>(part, bias, out);
}

// Round 10
// 33.916 us; speedup vs baseline: 10.3808x; 1.8498x over previous
//
#include <hip/hip_runtime.h>
#include <hip/hip_bf16.h>

// GNN layer: out = (A @ x) @ W^T + bias,  A = fixed 8-neighbor stencil.
// x[64][65536] f32, W[256][65536] f32, bias[256], out[64][256] f32.
// R10: FUSED stencil+gemm kernel (h1 lives only in LDS), bf16 partials,
// deterministic reduce. 2 launches total.

#define MB    64
#define NOUT  256
#define KDIM  65536
#define NTOT  (MB * KDIM)
#define KSP   256               // k-span per block
#define NCH   (KDIM / KSP)      // 256 chunks / blocks
#define OTOT  (MB * NOUT)       // 16384
#define LSTR  272               // LDS row stride in ushorts (544 B: quad spread)

typedef __attribute__((ext_vector_type(8))) short bf16x8;
typedef __attribute__((ext_vector_type(8))) unsigned short ushort8v;
typedef __attribute__((ext_vector_type(4))) float f32x4;

__device__ __forceinline__ ushort f2bf(float f) {
    __hip_bfloat16 h = __float2bfloat16(f);
    return *reinterpret_cast<ushort*>(&h);
}
__device__ __forceinline__ float bf2f(ushort u) {
    return __uint_as_float((unsigned)u << 16);
}

// ---------------------------------------------------------------------------
// Stencil: 8 bf16 h1 values at flat index g.  h1[b,i] = x[b,i] +
// sum_o ([center(i)]+[center(i+o)])*x[b,i+o]; centers = flat 257..65278
// (matches reference COO). Clamped OOB loads only feed weight-0 terms;
// cross-batch touches are provably weight-0 (centers are >=257 from edges).
// ---------------------------------------------------------------------------
__device__ __forceinline__ ushort8v stencil8v(const float* __restrict__ x, int g) {
    const int i8 = g & (KDIM - 1);
    union Span { float4 v[4]; float f[16]; };
    Span u, c, d;
    #pragma unroll
    for (int q = 0; q < 4; ++q) {
        int bu = g - 260 + 4 * q; if (bu < 0) bu = 0;
        int bc = g - 4   + 4 * q; if (bc < 0) bc = 0; if (bc > NTOT - 4) bc = NTOT - 4;
        int bd = g + 252 + 4 * q; if (bd > NTOT - 4) bd = NTOT - 4;
        u.v[q] = *(const float4*)(x + bu);
        c.v[q] = *(const float4*)(x + bc);
        d.v[q] = *(const float4*)(x + bd);
    }
    ushort8v ov;
    if (i8 >= 520 && i8 <= 65008) {          // fast path: everything interior
        #pragma unroll
        for (int e = 0; e < 8; ++e) {
            float nb = c.f[3 + e] + c.f[5 + e]
                     + u.f[3 + e] + u.f[4 + e] + u.f[5 + e]
                     + d.f[3 + e] + d.f[4 + e] + d.f[5 + e];
            ov[e] = (short)f2bf(fmaf(2.0f, nb, c.f[4 + e]));
        }
    } else {
        #pragma unroll
        for (int e = 0; e < 8; ++e) {
            const int ii = i8 + e;
            const float ci = ((unsigned)(ii - 257) <= (65278u - 257u)) ? 1.0f : 0.0f;
            float s = c.f[4 + e];
            const int   doff[8] = {-1, 1, -257, -256, -255, 255, 256, 257};
            const float* src[8] = {&c.f[3 + e], &c.f[5 + e],
                                   &u.f[3 + e], &u.f[4 + e], &u.f[5 + e],
                                   &d.f[3 + e], &d.f[4 + e], &d.f[5 + e]};
            #pragma unroll
            for (int t = 0; t < 8; ++t) {
                const int j = ii + doff[t];
                const float cj = ((unsigned)(j - 257) <= (65278u - 257u)) ? 1.0f : 0.0f;
                s = fmaf(ci + cj, *src[t], s);
            }
            ov[e] = (short)f2bf(s);
        }
    }
    return ov;
}

// ---------------------------------------------------------------------------
// FUSED kernel. Block = k-chunk kp (256 blocks = 1/CU). 1024 threads.
// Phase A: h1 slice [64 m][256 k] -> LDS (bf16, padded stride 272).
// Phase B: wave nt (16 waves): A-frags from LDS, W streamed f32->bf16,
//          MFMA over 4 m-tiles x 8 k-steps; bf16 partial [kp][n][m].
// XCD-chunked dispatch: kp = (b%8)*32 + b/8 -> consecutive kp per XCD
// share the x halo in that XCD's L2.
// ---------------------------------------------------------------------------
__global__ __launch_bounds__(1024, 4) void fused_sg(const float* __restrict__ x,
                                                    const float* __restrict__ W,
                                                    ushort* __restrict__ part) {
    __shared__ ushort hs[MB * LSTR];     // 34816 B
    const int b  = blockIdx.x;
    const int kp = (b & 7) * 32 + (b >> 3);      // 0..255
    const int t  = threadIdx.x;

    // ---- Phase A: stencil -> LDS ----
    {
        const int m = t >> 4;                    // 0..63
        const int j = t & 15;                    // 0..15 -> k-offset j*16
        const int g = m * KDIM + kp * KSP + j * 16;
        ushort8v o0 = stencil8v(x, g);
        ushort8v o1 = stencil8v(x, g + 8);
        *(ushort8v*)&hs[m * LSTR + j * 16]     = o0;
        *(ushort8v*)&hs[m * LSTR + j * 16 + 8] = o1;
    }
    __syncthreads();

    // ---- Phase B: MFMA gemm ----
    const int nt = t >> 6;                       // 0..15 n-tile
    const int l  = t & 63;
    const int lr = l & 15;
    const int lg = l >> 4;

    f32x4 acc[4];
    #pragma unroll
    for (int a = 0; a < 4; ++a) acc[a] = (f32x4){0.f, 0.f, 0.f, 0.f};

    const float* wp = W + (size_t)(nt * 16 + lr) * KDIM + kp * KSP + lg * 8;

    #pragma unroll
    for (int ks = 0; ks < KSP / 32; ++ks) {      // 8 fully-unrolled steps
        float4 w0 = *(const float4*)(wp + ks * 32);
        float4 w1 = *(const float4*)(wp + ks * 32 + 4);
        bf16x8 afrag[4];
        #pragma unroll
        for (int mt = 0; mt < 4; ++mt)
            afrag[mt] = *(const bf16x8*)&hs[(mt * 16 + lr) * LSTR + lg * 8 + ks * 32];
        union { ushort u[8]; bf16x8 v; } bb;
        bb.u[0] = f2bf(w0.x); bb.u[1] = f2bf(w0.y);
        bb.u[2] = f2bf(w0.z); bb.u[3] = f2bf(w0.w);
        bb.u[4] = f2bf(w1.x); bb.u[5] = f2bf(w1.y);
        bb.u[6] = f2bf(w1.z); bb.u[7] = f2bf(w1.w);
        #pragma unroll
        for (int mt = 0; mt < 4; ++mt)
            acc[mt] = __builtin_amdgcn_mfma_f32_16x16x32_bf16(afrag[mt], bb.v,
                                                              acc[mt], 0, 0, 0);
    }

    // D layout: n-col = lane&15, m = (lane>>4)*4 + reg (m89/m91-verified).
    // part[kp][n][m]: lane's 4 m are consecutive -> one ushort4 store.
    ushort* pb = part + (size_t)kp * OTOT + (size_t)(nt * 16 + lr) * MB;
    #pragma unroll
    for (int mt = 0; mt < 4; ++mt) {
        ushort4 s;
        s.x = f2bf(acc[mt][0]); s.y = f2bf(acc[mt][1]);
        s.z = f2bf(acc[mt][2]); s.w = f2bf(acc[mt][3]);
        *(ushort4*)(pb + mt * 16 + lg * 4) = s;
    }
}

// ---------------------------------------------------------------------------
// Reduce 256 bf16 partials (+bias) -> f32 out[64][256].
// 512 blocks x 256 thr: 8 threads/output, 32 chunks each, LDS combine.
// part[kc][n*64+m]; out[m][n].
// ---------------------------------------------------------------------------
__global__ __launch_bounds__(256) void reduce_bf16(const ushort* __restrict__ part,
                                                   const float* __restrict__ bias,
                                                   float* __restrict__ out) {
    __shared__ float red[256];
    const int ol = threadIdx.x & 31;
    const int cg = threadIdx.x >> 5;             // 0..7 -> 32 chunks each
    const int o  = blockIdx.x * 32 + ol;         // 0..16383
    const ushort* p = part + (size_t)cg * 32 * OTOT + o;
    float s0 = 0.f, s1 = 0.f, s2 = 0.f, s3 = 0.f;
    #pragma unroll 2
    for (int i = 0; i < 32; i += 4) {
        s0 += bf2f(p[(size_t)(i + 0) * OTOT]);
        s1 += bf2f(p[(size_t)(i + 1) * OTOT]);
        s2 += bf2f(p[(size_t)(i + 2) * OTOT]);
        s3 += bf2f(p[(size_t)(i + 3) * OTOT]);
    }
    red[threadIdx.x] = (s0 + s1) + (s2 + s3);
    __syncthreads();
    if (cg == 0) {
        float v = red[ol];
        #pragma unroll
        for (int jj = 1; jj < 8; ++jj) v += red[jj * 32 + ol];
        const int n = o >> 6, m = o & 63;
        out[m * NOUT + n] = v + bias[n];
    }
}

// ---------------------------------------------------------------------------
extern "C" void kernel_launch(void* const* d_in, const int* in_sizes, int n_in,
                              void* d_out, int out_size, void* d_ws, size_t ws_size,
                              hipStream_t stream) {
    const float* x    = (const float*)d_in[0];
    const float* W    = (const float*)d_in[1];
    const float* bias = (const float*)d_in[2];
    float* out = (float*)d_out;

    ushort* part = (ushort*)d_ws;                // 256*16384*2 = 8 MiB

    fused_sg<<<NCH, 1024, 0, stream>>>(x, W, part);
    reduce_bf16<<<OTOT / 32, 256, 0, stream>>>(part, bias, out);
}